// Round 10
// baseline (123.897 us; speedup 1.0000x reference)
//
#include <hip/hip_runtime.h>
#include <hip/hip_bf16.h>

#define NTOK 64
#define CDIM 128
#define SCALE 0.17677669529663688f   // 1/sqrt(32), folded into Wq/bq

typedef __attribute__((ext_vector_type(4))) float  f32x4;
typedef __attribute__((ext_vector_type(8))) short  bf16x8;
typedef __attribute__((ext_vector_type(4))) short  s16x4;

__device__ __forceinline__ unsigned pk2u(float a, float b) {
  union { __hip_bfloat162 h; unsigned u; } c;
  c.h = __float22bfloat162_rn(float2{a, b});
  return c.u;
}
__device__ __forceinline__ s16x4 pk4(f32x4 v) {
  union { unsigned u[2]; s16x4 s; } r;
  r.u[0] = pk2u(v.x, v.y); r.u[1] = pk2u(v.z, v.w);
  return r.s;
}

struct CPack { unsigned p0, p1; };
__device__ __forceinline__ CPack packC(f32x4 v) {
  CPack c; c.p0 = pk2u(v.x, v.y); c.p1 = pk2u(v.z, v.w); return c;
}

// C-layout -> MFMA A/B-frag repack (in-register). Validated R5/R6/R9.
__device__ __forceinline__ bf16x8 gatherFrag(CPack t0, CPack t1, int li, int g) {
  int L0 = ((g & 1) * 2) * 16 + li;
  int L1 = L0 + 16;
  unsigned a0 = __shfl(t0.p0, L0, 64), a1 = __shfl(t0.p1, L0, 64);
  unsigned a2 = __shfl(t0.p0, L1, 64), a3 = __shfl(t0.p1, L1, 64);
  unsigned b0 = __shfl(t1.p0, L0, 64), b1 = __shfl(t1.p1, L0, 64);
  unsigned b2 = __shfl(t1.p0, L1, 64), b3 = __shfl(t1.p1, L1, 64);
  bool hi = (g & 2) != 0;
  union { unsigned u[4]; bf16x8 v; } r;
  r.u[0] = hi ? b0 : a0; r.u[1] = hi ? b1 : a1;
  r.u[2] = hi ? b2 : a2; r.u[3] = hi ? b3 : a3;
  return r.v;
}

// XOR-swizzle within a 256B row: 16B granule, 3 row bits (validated R2)
__device__ __forceinline__ int swz(int row, int cb, int stride) {
  return row * stride + (cb ^ ((row & 7) << 4));
}

__global__ void wconv_kernel(const float* __restrict__ wq, const float* __restrict__ wk,
                             const float* __restrict__ wv, const float* __restrict__ wo,
                             short* __restrict__ wbf) {
  int t = (blockIdx.x * 256 + threadIdx.x) * 4;   // 16 blocks
  f32x4 a = *reinterpret_cast<const f32x4*>(wq + t);
  a.x *= SCALE; a.y *= SCALE; a.z *= SCALE; a.w *= SCALE;   // fold softmax scale into Wq
  f32x4 b = *reinterpret_cast<const f32x4*>(wk + t);
  f32x4 c = *reinterpret_cast<const f32x4*>(wv + t);
  f32x4 d = *reinterpret_cast<const f32x4*>(wo + t);
  *reinterpret_cast<s16x4*>(wbf + t)         = pk4(a);
  *reinterpret_cast<s16x4*>(wbf + 16384 + t) = pk4(b);
  *reinterpret_cast<s16x4*>(wbf + 32768 + t) = pk4(c);
  *reinterpret_cast<s16x4*>(wbf + 49152 + t) = pk4(d);
}

// LDS 32KB (4+ blocks/CU), cross-wave data only:
//   A [0,16K):   X -> K -> O
//   B [16K,32K): Q
// V and P are wave-private -> registers (gatherFrag). 5 barriers total.
#define A_OFF 0
#define B_OFF 16384
#define SMEM_BYTES 32768

__global__ __launch_bounds__(256, 3) void fused_attn(
    const float* __restrict__ x, const float* __restrict__ ent,
    const short* __restrict__ wbf,
    const float* __restrict__ bq, const float* __restrict__ bk,
    const float* __restrict__ bv, const float* __restrict__ bo,
    const int* __restrict__ beta, float* __restrict__ out)
{
  __shared__ unsigned char sm[SMEM_BYTES];
  const int tid  = threadIdx.x;
  const int lane = tid & 63;
  const int w    = tid >> 6;        // wave id 0..3 (= head id in attn phases)
  const int g    = lane >> 4;       // 16-lane group 0..3
  const int li   = lane & 15;
  const int b    = blockIdx.x;

  // ---------- phase 0: stage X (fp32 -> bf16, swizzled) into A ----------
  {
    const float* xb = x + (size_t)b * (NTOK * CDIM);
    #pragma unroll
    for (int it = 0; it < 8; ++it) {
      int f = (tid + 256 * it) * 4;
      int row = f >> 7, col = f & 127;
      f32x4 v = *reinterpret_cast<const f32x4*>(xb + f);
      *reinterpret_cast<s16x4*>(sm + A_OFF + swz(row, col * 2, 256)) = pk4(v);
    }
  }
  __syncthreads();   // B0: X staged

  // Preload all X fragments
  bf16x8 xf[4][4];
  #pragma unroll
  for (int ti = 0; ti < 4; ++ti)
    #pragma unroll
    for (int kk = 0; kk < 4; ++kk)
      xf[ti][kk] = *reinterpret_cast<const bf16x8*>(sm + A_OFF + swz(ti * 16 + li, (kk * 32 + g * 8) * 2, 256));

  __syncthreads();   // B1: X in regs; region A may be overwritten

  const f32x4 zero4 = {0.f, 0.f, 0.f, 0.f};

  // ---------- phase 1a: V (own head w) -> in-register PV A-frags ----------
  bf16x8 vA[2][2];   // [md2 (d tile)][ks (j half)]
  {
    const short* wv_ = wbf + 32768 + (w * 32) * CDIM;
    #pragma unroll
    for (int n2 = 0; n2 < 2; ++n2) {
      bf16x8 bfv[4];
      #pragma unroll
      for (int kk = 0; kk < 4; ++kk)
        bfv[kk] = *reinterpret_cast<const bf16x8*>(wv_ + (n2 * 16 + li) * CDIM + kk * 32 + g * 8);
      f32x4 vacc[4];
      #pragma unroll
      for (int mi = 0; mi < 4; ++mi) vacc[mi] = zero4;
      #pragma unroll
      for (int mi = 0; mi < 4; ++mi)
        #pragma unroll
        for (int kk = 0; kk < 4; ++kk)
          vacc[mi] = __builtin_amdgcn_mfma_f32_16x16x32_bf16(xf[mi][kk], bfv[kk], vacc[mi], 0, 0, 0);
      float bb = bv[w * 32 + n2 * 16 + li];
      #pragma unroll
      for (int mi = 0; mi < 4; ++mi) {
        vacc[mi].x += bb; vacc[mi].y += bb; vacc[mi].z += bb; vacc[mi].w += bb;
      }
      #pragma unroll
      for (int ks = 0; ks < 2; ++ks)
        vA[n2][ks] = gatherFrag(packC(vacc[ks * 2]), packC(vacc[ks * 2 + 1]), li, g);
    }
  }

  // ---------- phase 1b: Q,K (swapped: Dt = W * X^T), streamed per 16-dout tile ----------
  // waves 0,1 -> Q into B ; waves 2,3 -> K into A
  {
    const short* wmat = wbf + ((w < 2) ? 0 : 16384);
    const float* bias = (w < 2) ? bq : bk;
    const float bsc   = (w < 2) ? SCALE : 1.0f;
    const int dbase   = (w & 1) * 64;
    const int qkoff   = (w < 2) ? B_OFF : A_OFF;

    #pragma unroll
    for (int mi = 0; mi < 4; ++mi) {
      bf16x8 af[4];
      #pragma unroll
      for (int kk = 0; kk < 4; ++kk)
        af[kk] = *reinterpret_cast<const bf16x8*>(wmat + (dbase + mi * 16 + li) * CDIM + kk * 32 + g * 8);
      f32x4 acc[4];
      #pragma unroll
      for (int ni = 0; ni < 4; ++ni) acc[ni] = zero4;
      #pragma unroll
      for (int ni = 0; ni < 4; ++ni)
        #pragma unroll
        for (int kk = 0; kk < 4; ++kk)
          acc[ni] = __builtin_amdgcn_mfma_f32_16x16x32_bf16(af[kk], xf[ni][kk], acc[ni], 0, 0, 0);
      int d0 = dbase + mi * 16 + g * 4;
      float4 b4 = *reinterpret_cast<const float4*>(bias + d0);
      b4.x *= bsc; b4.y *= bsc; b4.z *= bsc; b4.w *= bsc;
      #pragma unroll
      for (int ni = 0; ni < 4; ++ni) {
        f32x4 v = acc[ni];
        v.x += b4.x; v.y += b4.y; v.z += b4.z; v.w += b4.w;
        *reinterpret_cast<s16x4*>(sm + qkoff + swz(ni * 16 + li, d0 * 2, 256)) = pk4(v);
      }
    }
  }
  __syncthreads();   // B2: Q,K ready

  // ---------- phase 2: scores (St = K * Q^T) + no-max softmax + PV, fused per i-tile ----------
  float4 gv[4];
  {
    const float nb = -(float)beta[0];
    const float* eb = ent + (size_t)b * NTOK;
    #pragma unroll
    for (int mj = 0; mj < 4; ++mj) {
      float4 e = *reinterpret_cast<const float4*>(eb + mj * 16 + g * 4);
      gv[mj].x = nb * e.x; gv[mj].y = nb * e.y; gv[mj].z = nb * e.z; gv[mj].w = nb * e.w;
    }
  }

  f32x4 accO[2][4];
  #pragma unroll
  for (int md2 = 0; md2 < 2; ++md2)
    #pragma unroll
    for (int ni = 0; ni < 4; ++ni) accO[md2][ni] = zero4;

  {
    bf16x8 kf[4], qf[4];
    int cb = (w * 32 + g * 8) * 2;   // d-range of head w
    #pragma unroll
    for (int t = 0; t < 4; ++t) {
      kf[t] = *reinterpret_cast<const bf16x8*>(sm + A_OFF + swz(t * 16 + li, cb, 256));
      qf[t] = *reinterpret_cast<const bf16x8*>(sm + B_OFF + swz(t * 16 + li, cb, 256));
    }
    #pragma unroll
    for (int ni = 0; ni < 4; ++ni) {
      f32x4 sc[4];
      #pragma unroll
      for (int mj = 0; mj < 4; ++mj)
        sc[mj] = __builtin_amdgcn_mfma_f32_16x16x32_bf16(kf[mj], qf[ni], zero4, 0, 0, 0);
      float sum = 0.f;
      #pragma unroll
      for (int mj = 0; mj < 4; ++mj) {
        f32x4 v = sc[mj];
        v.x = __expf(v.x + gv[mj].x); v.y = __expf(v.y + gv[mj].y);
        v.z = __expf(v.z + gv[mj].z); v.w = __expf(v.w + gv[mj].w);
        sc[mj] = v;
        sum += v.x + v.y + v.z + v.w;
      }
      sum += __shfl_xor(sum, 16);
      sum += __shfl_xor(sum, 32);
      float inv = 1.f / (sum + 1e-9f);
      #pragma unroll
      for (int mj = 0; mj < 4; ++mj) {
        sc[mj].x *= inv; sc[mj].y *= inv; sc[mj].z *= inv; sc[mj].w *= inv;
      }
      bf16x8 pf0 = gatherFrag(packC(sc[0]), packC(sc[1]), li, g);   // j half 0
      bf16x8 pf1 = gatherFrag(packC(sc[2]), packC(sc[3]), li, g);   // j half 1
      #pragma unroll
      for (int md2 = 0; md2 < 2; ++md2) {
        accO[md2][ni] = __builtin_amdgcn_mfma_f32_16x16x32_bf16(vA[md2][0], pf0, accO[md2][ni], 0, 0, 0);
        accO[md2][ni] = __builtin_amdgcn_mfma_f32_16x16x32_bf16(vA[md2][1], pf1, accO[md2][ni], 0, 0, 0);
      }
    }
  }
  __syncthreads();   // B3: all Q/K reads done; A may hold O

  // ---------- phase 3: O exchange: Ot[d][i] -> O[i][c] in A ----------
  #pragma unroll
  for (int md2 = 0; md2 < 2; ++md2) {
    int cb = (w * 32 + md2 * 16 + g * 4) * 2;
    #pragma unroll
    for (int ni = 0; ni < 4; ++ni)
      *reinterpret_cast<s16x4*>(sm + A_OFF + swz(ni * 16 + li, cb, 256)) = pk4(accO[md2][ni]);
  }
  __syncthreads();   // B4: O ready

  // ---------- phase 4: out-proj swapped (Yt = Wo * O^T) -> float4 stores ----------
  {
    const short* wo_ = wbf + 49152;
    f32x4 accY[2][4];   // [mi (dout tile)][ni (i tile)]
    #pragma unroll
    for (int mi = 0; mi < 2; ++mi)
      #pragma unroll
      for (int ni = 0; ni < 4; ++ni) accY[mi][ni] = zero4;
    bf16x8 wfa[2][4];
    #pragma unroll
    for (int mi = 0; mi < 2; ++mi)
      #pragma unroll
      for (int kk = 0; kk < 4; ++kk)
        wfa[mi][kk] = *reinterpret_cast<const bf16x8*>(wo_ + (w * 32 + mi * 16 + li) * CDIM + kk * 32 + g * 8);
    #pragma unroll
    for (int ni = 0; ni < 4; ++ni)
      #pragma unroll
      for (int kk = 0; kk < 4; ++kk) {
        bf16x8 of = *reinterpret_cast<const bf16x8*>(sm + A_OFF + swz(ni * 16 + li, (kk * 32 + g * 8) * 2, 256));
        accY[0][ni] = __builtin_amdgcn_mfma_f32_16x16x32_bf16(wfa[0][kk], of, accY[0][ni], 0, 0, 0);
        accY[1][ni] = __builtin_amdgcn_mfma_f32_16x16x32_bf16(wfa[1][kk], of, accY[1][ni], 0, 0, 0);
      }
    float* yb = out + (size_t)b * (NTOK * CDIM);
    #pragma unroll
    for (int mi = 0; mi < 2; ++mi) {
      int dout0 = w * 32 + mi * 16 + g * 4;
      float4 bo4 = *reinterpret_cast<const float4*>(bo + dout0);
      #pragma unroll
      for (int ni = 0; ni < 4; ++ni) {
        int i = ni * 16 + li;
        f32x4 y = accY[mi][ni];
        y.x += bo4.x; y.y += bo4.y; y.z += bo4.z; y.w += bo4.w;
        *reinterpret_cast<f32x4*>(yb + i * CDIM + dout0) = y;
      }
    }
  }
}

extern "C" void kernel_launch(void* const* d_in, const int* in_sizes, int n_in,
                              void* d_out, int out_size, void* d_ws, size_t ws_size,
                              hipStream_t stream) {
  const float* x    = (const float*)d_in[0];
  const float* ent  = (const float*)d_in[1];
  const float* wq   = (const float*)d_in[2];
  const float* bq   = (const float*)d_in[3];
  const float* wk   = (const float*)d_in[4];
  const float* bk   = (const float*)d_in[5];
  const float* wv   = (const float*)d_in[6];
  const float* bv   = (const float*)d_in[7];
  const float* wo   = (const float*)d_in[8];
  const float* bo   = (const float*)d_in[9];
  const int*   beta = (const int*)d_in[10];

  short* wbf = (short*)d_ws;             // 4 x 128x128 bf16 = 128 KB
  const int B = in_sizes[0] / (NTOK * CDIM);

  wconv_kernel<<<16, 256, 0, stream>>>(wq, wk, wv, wo, wbf);
  fused_attn<<<B, 256, 0, stream>>>(x, ent, wbf, bq, bk, bv, bo, beta, (float*)d_out);
}